// Round 24
// baseline (62.247 us; speedup 1.0000x reference)
//
#include <hip/hip_runtime.h>
#include <cfloat>

#define TOKENS 16384   // B*N
#define DDIM   2048
#define NEXP   128
#define KTOP   8
#define MB     64      // tokens per block
#define CH     64      // k elements per chunk
#define NCH    (DDIM / CH)   // 32
#define NCHH   (NCH / 2)     // 16 chunks per K-half (split-K)
#define NTHR   512

typedef float    f32x4 __attribute__((ext_vector_type(4)));
typedef _Float16 f16x8 __attribute__((ext_vector_type(8)));

// W fragment tables in d_ws (rebuilt each launch):
//   WFH[((eb*NCH + c)*2 + ks)*64 + lane] : uint4 = 8 fp16  wh = fp16(w)
//   WFM = WFH + WFRAG_N                 : 8 fp16  wm = fp16((w - wh)*4096)
#define WFRAG_N (8 * NCH * 2 * 64)   // 32768 uint4 per table (512 KB)

__device__ __forceinline__ unsigned short f16bits(float f) {
    _Float16 h = (_Float16)f;                      // RNE
    return __builtin_bit_cast(unsigned short, h);
}
__device__ __forceinline__ float f16tof(unsigned short u) {
    return (float)__builtin_bit_cast(_Float16, u); // exact
}

__global__ __launch_bounds__(256, 1) void wfrag_kernel(
    const float* __restrict__ W, uint4* __restrict__ wf)
{
    int id   = blockIdx.x * 256 + threadIdx.x;   // 0..32767
    int lane = id & 63;
    int ks   = (id >> 6) & 1;
    int c    = (id >> 7) & (NCH - 1);
    int eb   = id >> 12;
    int e    = eb * 16 + (lane & 15);
    int k0   = c * CH + ks * 32 + (lane >> 4) * 8;
    const float4* src = (const float4*)(W + (size_t)e * DDIM + k0);
    float4 a = src[0], bq = src[1];
    float v[8] = {a.x, a.y, a.z, a.w, bq.x, bq.y, bq.z, bq.w};
    unsigned hw[4], mw[4];
#pragma unroll
    for (int p = 0; p < 4; ++p) {
        unsigned short h0 = f16bits(v[2 * p]), h1 = f16bits(v[2 * p + 1]);
        unsigned short m0 = f16bits((v[2 * p]     - f16tof(h0)) * 4096.0f);
        unsigned short m1 = f16bits((v[2 * p + 1] - f16tof(h1)) * 4096.0f);
        hw[p] = (unsigned)h0 | ((unsigned)h1 << 16);
        mw[p] = (unsigned)m0 | ((unsigned)m1 << 16);
    }
    wf[id]           = make_uint4(hw[0], hw[1], hw[2], hw[3]);
    wf[WFRAG_N + id] = make_uint4(mw[0], mw[1], mw[2], mw[3]);
}

// branchless sorted-insert into descending top-8 list.
// strict '>' => ties keep the earlier (lower) index, matching jax.lax.top_k.
__device__ __forceinline__ void insert8(float (&vals)[8], int (&idxs)[8], float v, int e) {
    bool c[8];
#pragma unroll
    for (int p = 0; p < 8; ++p) c[p] = v > vals[p];
#pragma unroll
    for (int p = 7; p >= 1; --p) {
        vals[p] = c[p] ? (c[p - 1] ? vals[p - 1] : v) : vals[p];
        idxs[p] = c[p] ? (c[p - 1] ? idxs[p - 1] : e) : idxs[p];
    }
    vals[0] = c[0] ? v : vals[0];
    idxs[0] = c[0] ? e : idxs[0];
}

__device__ __forceinline__ void chunk_barrier() {
    asm volatile("s_waitcnt lgkmcnt(0)" ::: "memory");
    __builtin_amdgcn_sched_barrier(0);
    __builtin_amdgcn_s_barrier();
    __builtin_amdgcn_sched_barrier(0);
}

// ---------------- split-K GEMM: one K-half per block ----------------
// grid 512: bi>>1 = token tile, bi&1 = K-half. 16-chunk serial chain
// (half of R18's 32) with 2 blocks/CU overlapping. Same per-wave work per
// chunk as R18, same TOTAL x/W traffic. Writes per-half merged partial
// p = fmaf(acc2, 2^-12, acc1) to pl[half][tok][exp] (f32).
__global__ __launch_bounds__(NTHR, 1) void router_split_kernel(
    const float* __restrict__ x, const uint4* __restrict__ wf,
    float* __restrict__ pl)
{
    __shared__ __align__(16) char smem[32768];   // xh dbuf @0,8192; xm @16384,24576

    const int tid  = threadIdx.x;
    const int lane = tid & 63;
    const int wid  = tid >> 6;
    const int bi   = blockIdx.x;
    const int kh   = bi & 1;                 // K-half
    const int tok0 = (bi >> 1) * MB;

    const uint4* WFH = wf;
    const uint4* WFM = wf + WFRAG_N;

    f32x4 acc1[4], acc2[4];
#pragma unroll
    for (int mf = 0; mf < 4; ++mf) {
        acc1[mf] = (f32x4){0.f, 0.f, 0.f, 0.f};
        acc2[mf] = (f32x4){0.f, 0.f, 0.f, 0.f};
    }

    const float4* x4 = (const float4*)x;
    const int xr0 = tid >> 4, xr1 = 32 + (tid >> 4), xq = tid & 15;
    // base includes this half's k-offset (kh * 16 chunks * 16 float4)
    const size_t xoff0 = (size_t)(tok0 + xr0) * (DDIM / 4) + (size_t)kh * NCHH * 16 + xq;
    const size_t xoff1 = (size_t)(tok0 + xr1) * (DDIM / 4) + (size_t)kh * NCHH * 16 + xq;
    const int xb0 = xr0 * 128 + (((xq >> 1) ^ (xr0 & 7)) << 4) + (xq & 1) * 8;
    const int xb1 = xr1 * 128 + (((xq >> 1) ^ (xr1 & 7)) << 4) + (xq & 1) * 8;

    float4 S0[2], S1[2], S2[2], S3[2], S4[2], S5[2], S6[2], S7[2];
    uint4  wA[4], wB[4];

    auto loadX = [&](int cr, float4 (&S)[2]) {
        S[0] = x4[xoff0 + (size_t)cr * 16];
        S[1] = x4[xoff1 + (size_t)cr * 16];
    };
    auto loadW = [&](int cr, uint4 (&wreg)[4]) {
        const int ca = kh * NCHH + cr;       // absolute chunk
#pragma unroll
        for (int ks = 0; ks < 2; ++ks) {
            int idx = ((wid * NCH + ca) * 2 + ks) * 64 + lane;
            wreg[ks]     = WFH[idx];
            wreg[2 + ks] = WFM[idx];
        }
    };
    auto convertX = [&](const float4 (&sx)[2], char* ldsDst) {
#pragma unroll
        for (int r = 0; r < 2; ++r) {
            const float4 v = sx[r];
            unsigned short h0 = f16bits(v.x), h1 = f16bits(v.y);
            unsigned short h2 = f16bits(v.z), h3 = f16bits(v.w);
            unsigned short m0 = f16bits((v.x - f16tof(h0)) * 4096.0f);
            unsigned short m1 = f16bits((v.y - f16tof(h1)) * 4096.0f);
            unsigned short m2 = f16bits((v.z - f16tof(h2)) * 4096.0f);
            unsigned short m3 = f16bits((v.w - f16tof(h3)) * 4096.0f);
            uint2 hv = make_uint2((unsigned)h0 | ((unsigned)h1 << 16),
                                  (unsigned)h2 | ((unsigned)h3 << 16));
            uint2 mv = make_uint2((unsigned)m0 | ((unsigned)m1 << 16),
                                  (unsigned)m2 | ((unsigned)m3 << 16));
            const int byteoff = r ? xb1 : xb0;
            *(uint2*)(ldsDst + byteoff)         = hv;
            *(uint2*)(ldsDst + 16384 + byteoff) = mv;
        }
    };

    auto step = [&](int cr, float4 (&Sload)[2], float4 (&Scvt)[2],
                    uint4 (&wCur)[4], uint4 (&wNext)[4],
                    char* bufCur, char* bufNext) {
        if (cr + 8 < NCHH) loadX(cr + 8, Sload);
        if (cr + 1 < NCHH) loadW(cr + 1, wNext);

#pragma unroll
        for (int ks = 0; ks < 2; ++ks) {
            f16x8 ah[4], am[4];
#pragma unroll
            for (int mf = 0; mf < 4; ++mf) {
                int row = 16 * mf + (lane & 15);
                int byteoff = row * 128 +
                    ((((ks << 2) | (lane >> 4)) ^ (row & 7)) << 4);
                ah[mf] = *(const f16x8*)(bufCur + byteoff);
                am[mf] = *(const f16x8*)(bufCur + 16384 + byteoff);
            }
            f16x8 wh = __builtin_bit_cast(f16x8, wCur[ks]);
            f16x8 wm = __builtin_bit_cast(f16x8, wCur[2 + ks]);
#pragma unroll
            for (int mf = 0; mf < 4; ++mf) {
                acc1[mf] = __builtin_amdgcn_mfma_f32_16x16x32_f16(
                    ah[mf], wh, acc1[mf], 0, 0, 0);
                acc2[mf] = __builtin_amdgcn_mfma_f32_16x16x32_f16(
                    ah[mf], wm, acc2[mf], 0, 0, 0);
                acc2[mf] = __builtin_amdgcn_mfma_f32_16x16x32_f16(
                    am[mf], wh, acc2[mf], 0, 0, 0);
            }
        }

        if (cr + 1 < NCHH) convertX(Scvt, bufNext);
        chunk_barrier();
    };

    // prologue: x(0..7 rel), W(0 rel); convert x(0) -> buf0
    loadX(0, S0); loadX(1, S1);
    loadW(0, wA);
    loadX(2, S2); loadX(3, S3);
    loadX(4, S4); loadX(5, S5);
    loadX(6, S6); loadX(7, S7);
    convertX(S0, smem);
    chunk_barrier();

    char* buf0 = smem;
    char* buf1 = smem + 8192;
    for (int cc = 0; cc < NCHH; cc += 8) {
        step(cc,     S0, S1, wA, wB, buf0, buf1);
        step(cc + 1, S1, S2, wB, wA, buf1, buf0);
        step(cc + 2, S2, S3, wA, wB, buf0, buf1);
        step(cc + 3, S3, S4, wB, wA, buf1, buf0);
        step(cc + 4, S4, S5, wA, wB, buf0, buf1);
        step(cc + 5, S5, S6, wB, wA, buf1, buf0);
        step(cc + 6, S6, S7, wA, wB, buf0, buf1);
        step(cc + 7, S7, S0, wB, wA, buf1, buf0);
    }

    // write per-half merged partials (C/D: col=lane&15 -> expert,
    // row=(lane>>4)*4+reg -> token)
    float* plh = pl + (size_t)kh * TOKENS * NEXP;
#pragma unroll
    for (int mf = 0; mf < 4; ++mf)
#pragma unroll
        for (int r = 0; r < 4; ++r) {
            int t = 16 * mf + (lane >> 4) * 4 + r;
            int e = wid * 16 + (lane & 15);
            plh[(size_t)(tok0 + t) * NEXP + e] =
                fmaf(acc2[mf][r], 0.000244140625f, acc1[mf][r]);
        }
}

// ---------------- combine: add halves + bias, then proven epilogue --------
__global__ __launch_bounds__(NTHR, 1) void combine_kernel(
    const float* __restrict__ pl, const float* __restrict__ b,
    float* __restrict__ out_gates, float* __restrict__ out_idx)
{
    __shared__ __align__(16) char smem[52224];
    float* lg  = (float*)smem;                 // [64][132]
    float* plv = (float*)(smem + 33792);       // [256 lists][stride 9]
    int*   pli = (int*)(smem + 43008);

    const int tid  = threadIdx.x;
    const int tok0 = blockIdx.x * MB;

    const float4* p0 = (const float4*)pl;
    const float4* p1 = (const float4*)(pl + (size_t)TOKENS * NEXP);
    const float4* b4 = (const float4*)b;

    // logits = half0 + half1 + bias -> lg (coalesced float4)
    for (int f = tid; f < MB * (NEXP / 4); f += NTHR) {
        int m = f >> 5, e4 = f & 31;
        size_t gi = (size_t)(tok0 + m) * (NEXP / 4) + e4;
        float4 v0 = p0[gi], v1 = p1[gi], bb = b4[e4];
        float4 v;
        v.x = v0.x + v1.x + bb.x;
        v.y = v0.y + v1.y + bb.y;
        v.z = v0.z + v1.z + bb.z;
        v.w = v0.w + v1.w + bb.w;
        *(float4*)&lg[m * 132 + e4 * 4] = v;
    }
    __syncthreads();

    // partial top-8: 4 threads per token, 32 experts each
    if (tid < 256) {
        int tt = tid >> 2, p = tid & 3;
        float vals[8]; int idxs[8];
#pragma unroll
        for (int k = 0; k < 8; ++k) { vals[k] = -FLT_MAX; idxs[k] = 0; }
        const float* row = &lg[tt * 132 + p * 32];
        for (int q = 0; q < 32; ++q)
            insert8(vals, idxs, row[q], p * 32 + q);
#pragma unroll
        for (int k = 0; k < 8; ++k) {
            plv[tid * 9 + k] = vals[k];
            pli[tid * 9 + k] = idxs[k];
        }
    }
    __syncthreads();

    float g[8]; int fidx[8];
    const bool active = (tid < MB);
    if (active) {
        float vals[8]; int idxs[8];
#pragma unroll
        for (int k = 0; k < 8; ++k) { vals[k] = -FLT_MAX; idxs[k] = 0; }
        for (int p = 0; p < 4; ++p) {
#pragma unroll
            for (int k = 0; k < 8; ++k)
                insert8(vals, idxs, plv[(tid * 4 + p) * 9 + k], pli[(tid * 4 + p) * 9 + k]);
        }
        float mx = vals[0];
        float s = 0.0f;
#pragma unroll
        for (int k = 0; k < 8; ++k) { g[k] = __expf(vals[k] - mx); s += g[k]; }
        float inv = 1.0f / s;
#pragma unroll
        for (int k = 0; k < 8; ++k) { g[k] *= inv; fidx[k] = idxs[k]; }
#pragma unroll
        for (int k = 0; k < 8; ++k)
            out_idx[(size_t)(tok0 + tid) * KTOP + k] = (float)idxs[k];
    }
    for (int f = tid; f < MB * 132; f += NTHR) lg[f] = 0.0f;
    __syncthreads();

    if (active) {
#pragma unroll
        for (int k = 0; k < 8; ++k) lg[tid * 132 + fidx[k]] = g[k];
    }
    __syncthreads();

    for (int f = tid; f < MB * (NEXP / 4); f += NTHR) {
        int m = f >> 5, e4 = f & 31;
        float4 v = *(const float4*)&lg[m * 132 + e4 * 4];
        ((float4*)out_gates)[(size_t)(tok0 + m) * (NEXP / 4) + e4] = v;
    }
}

// ---------------- fallback: proven R18/R23 single-pass router ----------------
__global__ __launch_bounds__(NTHR, 1) void router_kernel(
    const float* __restrict__ x, const uint4* __restrict__ wf,
    const float* __restrict__ b, float* __restrict__ out_gates,
    float* __restrict__ out_idx)
{
    __shared__ __align__(16) char smem[52224];
    float* lg  = (float*)smem;
    float* plv = (float*)(smem + 33792);
    int*   pli = (int*)(smem + 43008);

    const int tid  = threadIdx.x;
    const int lane = tid & 63;
    const int wid  = tid >> 6;
    const int tok0 = blockIdx.x * MB;

    const uint4* WFH = wf;
    const uint4* WFM = wf + WFRAG_N;

    f32x4 acc1[4], acc2[4];
#pragma unroll
    for (int mf = 0; mf < 4; ++mf) {
        acc1[mf] = (f32x4){0.f, 0.f, 0.f, 0.f};
        acc2[mf] = (f32x4){0.f, 0.f, 0.f, 0.f};
    }

    const float4* x4 = (const float4*)x;
    const int xr0 = tid >> 4, xr1 = 32 + (tid >> 4), xq = tid & 15;
    const size_t xoff0 = (size_t)(tok0 + xr0) * (DDIM / 4) + xq;
    const size_t xoff1 = (size_t)(tok0 + xr1) * (DDIM / 4) + xq;
    const int xb0 = xr0 * 128 + (((xq >> 1) ^ (xr0 & 7)) << 4) + (xq & 1) * 8;
    const int xb1 = xr1 * 128 + (((xq >> 1) ^ (xr1 & 7)) << 4) + (xq & 1) * 8;

    float4 S0[2], S1[2], S2[2], S3[2], S4[2], S5[2], S6[2], S7[2];
    uint4  wA[4], wB[4];

    auto loadX = [&](int c, float4 (&S)[2]) {
        S[0] = x4[xoff0 + (size_t)c * 16];
        S[1] = x4[xoff1 + (size_t)c * 16];
    };
    auto loadW = [&](int c, uint4 (&wreg)[4]) {
#pragma unroll
        for (int ks = 0; ks < 2; ++ks) {
            int idx = ((wid * NCH + c) * 2 + ks) * 64 + lane;
            wreg[ks]     = WFH[idx];
            wreg[2 + ks] = WFM[idx];
        }
    };
    auto convertX = [&](const float4 (&sx)[2], char* ldsDst) {
#pragma unroll
        for (int r = 0; r < 2; ++r) {
            const float4 v = sx[r];
            unsigned short h0 = f16bits(v.x), h1 = f16bits(v.y);
            unsigned short h2 = f16bits(v.z), h3 = f16bits(v.w);
            unsigned short m0 = f16bits((v.x - f16tof(h0)) * 4096.0f);
            unsigned short m1 = f16bits((v.y - f16tof(h1)) * 4096.0f);
            unsigned short m2 = f16bits((v.z - f16tof(h2)) * 4096.0f);
            unsigned short m3 = f16bits((v.w - f16tof(h3)) * 4096.0f);
            uint2 hv = make_uint2((unsigned)h0 | ((unsigned)h1 << 16),
                                  (unsigned)h2 | ((unsigned)h3 << 16));
            uint2 mv = make_uint2((unsigned)m0 | ((unsigned)m1 << 16),
                                  (unsigned)m2 | ((unsigned)m3 << 16));
            const int byteoff = r ? xb1 : xb0;
            *(uint2*)(ldsDst + byteoff)         = hv;
            *(uint2*)(ldsDst + 16384 + byteoff) = mv;
        }
    };

    auto step = [&](int c, float4 (&Sload)[2], float4 (&Scvt)[2],
                    uint4 (&wCur)[4], uint4 (&wNext)[4],
                    char* bufCur, char* bufNext) {
        if (c + 8 < NCH) loadX(c + 8, Sload);
        if (c + 1 < NCH) loadW(c + 1, wNext);
#pragma unroll
        for (int ks = 0; ks < 2; ++ks) {
            f16x8 ah[4], am[4];
#pragma unroll
            for (int mf = 0; mf < 4; ++mf) {
                int row = 16 * mf + (lane & 15);
                int byteoff = row * 128 +
                    ((((ks << 2) | (lane >> 4)) ^ (row & 7)) << 4);
                ah[mf] = *(const f16x8*)(bufCur + byteoff);
                am[mf] = *(const f16x8*)(bufCur + 16384 + byteoff);
            }
            f16x8 wh = __builtin_bit_cast(f16x8, wCur[ks]);
            f16x8 wm = __builtin_bit_cast(f16x8, wCur[2 + ks]);
#pragma unroll
            for (int mf = 0; mf < 4; ++mf) {
                acc1[mf] = __builtin_amdgcn_mfma_f32_16x16x32_f16(
                    ah[mf], wh, acc1[mf], 0, 0, 0);
                acc2[mf] = __builtin_amdgcn_mfma_f32_16x16x32_f16(
                    ah[mf], wm, acc2[mf], 0, 0, 0);
                acc2[mf] = __builtin_amdgcn_mfma_f32_16x16x32_f16(
                    am[mf], wh, acc2[mf], 0, 0, 0);
            }
        }
        if (c + 1 < NCH) convertX(Scvt, bufNext);
        chunk_barrier();
    };

    loadX(0, S0); loadX(1, S1);
    loadW(0, wA);
    loadX(2, S2); loadX(3, S3);
    loadX(4, S4); loadX(5, S5);
    loadX(6, S6); loadX(7, S7);
    convertX(S0, smem);
    chunk_barrier();

    char* buf0 = smem;
    char* buf1 = smem + 8192;
    for (int cc = 0; cc < NCH; cc += 8) {
        step(cc,     S0, S1, wA, wB, buf0, buf1);
        step(cc + 1, S1, S2, wB, wA, buf1, buf0);
        step(cc + 2, S2, S3, wA, wB, buf0, buf1);
        step(cc + 3, S3, S4, wB, wA, buf1, buf0);
        step(cc + 4, S4, S5, wA, wB, buf0, buf1);
        step(cc + 5, S5, S6, wB, wA, buf1, buf0);
        step(cc + 6, S6, S7, wA, wB, buf0, buf1);
        step(cc + 7, S7, S0, wB, wA, buf1, buf0);
    }

    const float bb = b[wid * 16 + (lane & 15)];
#pragma unroll
    for (int mf = 0; mf < 4; ++mf)
#pragma unroll
        for (int r = 0; r < 4; ++r) {
            int t = 16 * mf + (lane >> 4) * 4 + r;
            int e = wid * 16 + (lane & 15);
            lg[t * 132 + e] =
                fmaf(acc2[mf][r], 0.000244140625f, acc1[mf][r]) + bb;
        }
    __syncthreads();

    if (tid < 256) {
        int tt = tid >> 2, p = tid & 3;
        float vals[8]; int idxs[8];
#pragma unroll
        for (int k = 0; k < 8; ++k) { vals[k] = -FLT_MAX; idxs[k] = 0; }
        const float* row = &lg[tt * 132 + p * 32];
        for (int q = 0; q < 32; ++q)
            insert8(vals, idxs, row[q], p * 32 + q);
#pragma unroll
        for (int k = 0; k < 8; ++k) {
            plv[tid * 9 + k] = vals[k];
            pli[tid * 9 + k] = idxs[k];
        }
    }
    __syncthreads();

    float g[8]; int fidx[8];
    const bool active = (tid < MB);
    if (active) {
        float vals[8]; int idxs[8];
#pragma unroll
        for (int k = 0; k < 8; ++k) { vals[k] = -FLT_MAX; idxs[k] = 0; }
        for (int p = 0; p < 4; ++p) {
#pragma unroll
            for (int k = 0; k < 8; ++k)
                insert8(vals, idxs, plv[(tid * 4 + p) * 9 + k], pli[(tid * 4 + p) * 9 + k]);
        }
        float mx = vals[0];
        float s = 0.0f;
#pragma unroll
        for (int k = 0; k < 8; ++k) { g[k] = __expf(vals[k] - mx); s += g[k]; }
        float inv = 1.0f / s;
#pragma unroll
        for (int k = 0; k < 8; ++k) { g[k] *= inv; fidx[k] = idxs[k]; }
#pragma unroll
        for (int k = 0; k < 8; ++k)
            out_idx[(size_t)(tok0 + tid) * KTOP + k] = (float)idxs[k];
    }
    for (int f = tid; f < MB * 132; f += NTHR) lg[f] = 0.0f;
    __syncthreads();

    if (active) {
#pragma unroll
        for (int k = 0; k < 8; ++k) lg[tid * 132 + fidx[k]] = g[k];
    }
    __syncthreads();

    for (int f = tid; f < MB * (NEXP / 4); f += NTHR) {
        int m = f >> 5, e4 = f & 31;
        float4 v = *(const float4*)&lg[m * 132 + e4 * 4];
        ((float4*)out_gates)[(size_t)(tok0 + m) * (NEXP / 4) + e4] = v;
    }
}

extern "C" void kernel_launch(void* const* d_in, const int* in_sizes, int n_in,
                              void* d_out, int out_size, void* d_ws, size_t ws_size,
                              hipStream_t stream) {
    const float* x = (const float*)d_in[0];   // [B,N,D] f32
    const float* W = (const float*)d_in[1];   // [E,D]   f32
    const float* b = (const float*)d_in[2];   // [E]     f32

    float* out_gates = (float*)d_out;                       // [B,N,E] f32
    float* out_idx   = out_gates + (size_t)TOKENS * NEXP;   // [B,N,K] as f32

    uint4* wf = (uint4*)d_ws;                               // 1 MB frag tables
    const size_t wf_bytes = (size_t)2 * WFRAG_N * sizeof(uint4);
    const size_t pl_bytes = (size_t)2 * TOKENS * NEXP * sizeof(float);  // 16 MB

    wfrag_kernel<<<dim3(WFRAG_N / 256), dim3(256), 0, stream>>>(W, wf);

    if (ws_size >= wf_bytes + pl_bytes) {
        float* pl = (float*)((char*)d_ws + wf_bytes);
        router_split_kernel<<<dim3(2 * TOKENS / MB), dim3(NTHR), 0, stream>>>(x, wf, pl);
        combine_kernel<<<dim3(TOKENS / MB), dim3(NTHR), 0, stream>>>(pl, b, out_gates, out_idx);
    } else {
        router_kernel<<<dim3(TOKENS / MB), dim3(NTHR), 0, stream>>>(x, wf, b, out_gates, out_idx);
    }
}

// Round 25
// 52.821 us; speedup vs baseline: 1.1784x; 1.1784x over previous
//
#include <hip/hip_runtime.h>
#include <cfloat>

#define TOKENS 16384   // B*N
#define DDIM   2048
#define NEXP   128
#define KTOP   8
#define MB     64      // tokens per block
#define CH     64      // k elements per chunk
#define NCH    (DDIM / CH)   // 32
#define NTHR   512     // 8 waves/block, grid 256 -> 1 block/CU

typedef float    f32x4 __attribute__((ext_vector_type(4)));
typedef _Float16 f16x8 __attribute__((ext_vector_type(8)));

// W fragment tables in d_ws (rebuilt each launch):
//   WFH[((eb*NCH + c)*2 + ks)*64 + lane] : uint4 = 8 fp16  wh = fp16(w)
//   WFM = WFH + WFRAG_N                 : 8 fp16  wm = fp16((w - wh)*4096)
// Slot j of lane l holds k = c*64 + ks*32 + (l>>4)*8 + j, expert = eb*16 + (l&15).
// The table PRE-COALESCES W into fragment order (R22: in-loop raw row loads
// are 16-lane x 8KB-stride = 16 lines/instr, -12us).
#define WFRAG_N (8 * NCH * 2 * 64)   // 32768 uint4 per table (512 KB)

__device__ __forceinline__ unsigned short f16bits(float f) {
    _Float16 h = (_Float16)f;                      // RNE
    return __builtin_bit_cast(unsigned short, h);
}
__device__ __forceinline__ float f16tof(unsigned short u) {
    return (float)__builtin_bit_cast(_Float16, u); // exact
}

__global__ __launch_bounds__(256, 1) void wfrag_kernel(
    const float* __restrict__ W, uint4* __restrict__ wf)
{
    int id   = blockIdx.x * 256 + threadIdx.x;   // 0..32767
    int lane = id & 63;
    int ks   = (id >> 6) & 1;
    int c    = (id >> 7) & (NCH - 1);
    int eb   = id >> 12;
    int e    = eb * 16 + (lane & 15);
    int k0   = c * CH + ks * 32 + (lane >> 4) * 8;
    const float4* src = (const float4*)(W + (size_t)e * DDIM + k0);
    float4 a = src[0], bq = src[1];      // vectorized loads
    float v[8] = {a.x, a.y, a.z, a.w, bq.x, bq.y, bq.z, bq.w};
    unsigned hw[4], mw[4];
#pragma unroll
    for (int p = 0; p < 4; ++p) {
        unsigned short h0 = f16bits(v[2 * p]), h1 = f16bits(v[2 * p + 1]);
        unsigned short m0 = f16bits((v[2 * p]     - f16tof(h0)) * 4096.0f);
        unsigned short m1 = f16bits((v[2 * p + 1] - f16tof(h1)) * 4096.0f);
        hw[p] = (unsigned)h0 | ((unsigned)h1 << 16);
        mw[p] = (unsigned)m0 | ((unsigned)m1 << 16);
    }
    wf[id]           = make_uint4(hw[0], hw[1], hw[2], hw[3]);
    wf[WFRAG_N + id] = make_uint4(mw[0], mw[1], mw[2], mw[3]);
}

// branchless sorted-insert into descending top-8 list.
// strict '>' => ties keep the earlier (lower) index, matching jax.lax.top_k.
__device__ __forceinline__ void insert8(float (&vals)[8], int (&idxs)[8], float v, int e) {
    bool c[8];
#pragma unroll
    for (int p = 0; p < 8; ++p) c[p] = v > vals[p];
#pragma unroll
    for (int p = 7; p >= 1; --p) {
        vals[p] = c[p] ? (c[p - 1] ? vals[p - 1] : v) : vals[p];
        idxs[p] = c[p] ? (c[p - 1] ? idxs[p - 1] : e) : idxs[p];
    }
    vals[0] = c[0] ? v : vals[0];
    idxs[0] = c[0] ? e : idxs[0];
}

// fp16-split MFMA router — FINAL: R18/R23 configuration (53.3us, reproduced
// twice; 26x over fp32 baseline). logit = xh*wh + (xh*wm + xm*wh)/4096,
// residuals pre-scaled 2^12; deviation ~3e-7 -> exact top-k (16x verified).
// 4-deep x register pipeline (the one paying lever: 62->54us), lgkm-only
// barrier, stride-9 epilogue lists. Falsified levers: occupancy (R11/R20),
// traffic (R12), barrier drain/period/existence (R13/R15/R16/R19), LDS
// volume (R14/R21), x-depth>16KB (R18), fusion (R22), split-K (R24).
__device__ __forceinline__ void chunk_barrier() {
    asm volatile("s_waitcnt lgkmcnt(0)" ::: "memory");
    __builtin_amdgcn_sched_barrier(0);
    __builtin_amdgcn_s_barrier();
    __builtin_amdgcn_sched_barrier(0);
}

__global__ __launch_bounds__(NTHR, 1) void router_kernel(
    const float* __restrict__ x, const uint4* __restrict__ wf,
    const float* __restrict__ b, float* __restrict__ out_gates,
    float* __restrict__ out_idx)
{
    // GEMM phase: xh dbuf @0,8192; xm dbuf @16384,24576 (32 KB total)
    // Epilogue overlay: lg [64][132] f32 @0 (33792);
    //   plv [256 lists][stride 9] @33792 (9216); pli @43008 (9216)
    __shared__ __align__(16) char smem[52224];
    float* lg  = (float*)smem;
    float* plv = (float*)(smem + 33792);
    int*   pli = (int*)(smem + 43008);

    const int tid  = threadIdx.x;
    const int lane = tid & 63;
    const int wid  = tid >> 6;           // wave 0..7 -> expert-block eb = wid
    const int tok0 = blockIdx.x * MB;

    const uint4* WFH = wf;
    const uint4* WFM = wf + WFRAG_N;

    f32x4 acc1[4], acc2[4];              // [mf] -> tokens 16*mf..16*mf+15
#pragma unroll
    for (int mf = 0; mf < 4; ++mf) {
        acc1[mf] = (f32x4){0.f, 0.f, 0.f, 0.f};
        acc2[mf] = (f32x4){0.f, 0.f, 0.f, 0.f};
    }

    const float4* x4 = (const float4*)x;
    // x staging: 512 threads stage 64 rows x 16 float4-cols (2 per thread)
    const int xr0 = tid >> 4, xr1 = 32 + (tid >> 4), xq = tid & 15;
    const size_t xoff0 = (size_t)(tok0 + xr0) * (DDIM / 4) + xq;
    const size_t xoff1 = (size_t)(tok0 + xr1) * (DDIM / 4) + xq;
    // swizzled LDS byte offsets (16B-slot ^= row&7); 8 B (4 fp16) per write
    const int xb0 = xr0 * 128 + (((xq >> 1) ^ (xr0 & 7)) << 4) + (xq & 1) * 8;
    const int xb1 = xr1 * 128 + (((xq >> 1) ^ (xr1 & 7)) << 4) + (xq & 1) * 8;

    float4 S0[2], S1[2], S2[2], S3[2], S4[2], S5[2], S6[2], S7[2];
    uint4  wA[4], wB[4];                 // [0..1]=wh (ks), [2..3]=wm (ks)

    auto loadX = [&](int c, float4 (&S)[2]) {
        S[0] = x4[xoff0 + (size_t)c * 16];
        S[1] = x4[xoff1 + (size_t)c * 16];
    };
    auto loadW = [&](int c, uint4 (&wreg)[4]) {
#pragma unroll
        for (int ks = 0; ks < 2; ++ks) {
            int idx = ((wid * NCH + c) * 2 + ks) * 64 + lane;
            wreg[ks]     = WFH[idx];
            wreg[2 + ks] = WFM[idx];
        }
    };
    auto convertX = [&](const float4 (&sx)[2], char* ldsDst) {
#pragma unroll
        for (int r = 0; r < 2; ++r) {
            const float4 v = sx[r];
            unsigned short h0 = f16bits(v.x), h1 = f16bits(v.y);
            unsigned short h2 = f16bits(v.z), h3 = f16bits(v.w);
            unsigned short m0 = f16bits((v.x - f16tof(h0)) * 4096.0f);
            unsigned short m1 = f16bits((v.y - f16tof(h1)) * 4096.0f);
            unsigned short m2 = f16bits((v.z - f16tof(h2)) * 4096.0f);
            unsigned short m3 = f16bits((v.w - f16tof(h3)) * 4096.0f);
            uint2 hv = make_uint2((unsigned)h0 | ((unsigned)h1 << 16),
                                  (unsigned)h2 | ((unsigned)h3 << 16));
            uint2 mv = make_uint2((unsigned)m0 | ((unsigned)m1 << 16),
                                  (unsigned)m2 | ((unsigned)m3 << 16));
            const int byteoff = r ? xb1 : xb0;
            *(uint2*)(ldsDst + byteoff)         = hv;
            *(uint2*)(ldsDst + 16384 + byteoff) = mv;
        }
    };

    // step at chunk c: issue x(c+8) into Sload (converted last chunk), issue
    // W(c+1), MFMA chunk c, convert Scvt (= x(c+1)) into the other buffer.
    auto step = [&](int c, float4 (&Sload)[2], float4 (&Scvt)[2],
                    uint4 (&wCur)[4], uint4 (&wNext)[4],
                    char* bufCur, char* bufNext) {
        if (c + 8 < NCH) loadX(c + 8, Sload);
        if (c + 1 < NCH) loadW(c + 1, wNext);

        // compute chunk c: 16 ds_read_b128 + 24 MFMAs per wave
#pragma unroll
        for (int ks = 0; ks < 2; ++ks) {
            f16x8 ah[4], am[4];
#pragma unroll
            for (int mf = 0; mf < 4; ++mf) {
                int row = 16 * mf + (lane & 15);
                int byteoff = row * 128 +
                    ((((ks << 2) | (lane >> 4)) ^ (row & 7)) << 4);
                ah[mf] = *(const f16x8*)(bufCur + byteoff);
                am[mf] = *(const f16x8*)(bufCur + 16384 + byteoff);
            }
            f16x8 wh = __builtin_bit_cast(f16x8, wCur[ks]);
            f16x8 wm = __builtin_bit_cast(f16x8, wCur[2 + ks]);
#pragma unroll
            for (int mf = 0; mf < 4; ++mf) {
                acc1[mf] = __builtin_amdgcn_mfma_f32_16x16x32_f16(
                    ah[mf], wh, acc1[mf], 0, 0, 0);
                acc2[mf] = __builtin_amdgcn_mfma_f32_16x16x32_f16(
                    ah[mf], wm, acc2[mf], 0, 0, 0);
                acc2[mf] = __builtin_amdgcn_mfma_f32_16x16x32_f16(
                    am[mf], wh, acc2[mf], 0, 0, 0);
            }
        }

        if (c + 1 < NCH) convertX(Scvt, bufNext);
        chunk_barrier();
    };

    // ---- prologue: x(0..7) in S0..S7, W(0); convert x(0) -> buf0 ----
    loadX(0, S0);
    loadX(1, S1);
    loadW(0, wA);
    loadX(2, S2);
    loadX(3, S3);
    loadX(4, S4);
    loadX(5, S5);
    loadX(6, S6);
    loadX(7, S7);
    convertX(S0, smem);
    chunk_barrier();

    char* buf0 = smem;
    char* buf1 = smem + 8192;
    for (int cc = 0; cc < NCH; cc += 8) {
        step(cc,     S0, S1, wA, wB, buf0, buf1);
        step(cc + 1, S1, S2, wB, wA, buf1, buf0);
        step(cc + 2, S2, S3, wA, wB, buf0, buf1);
        step(cc + 3, S3, S4, wB, wA, buf1, buf0);
        step(cc + 4, S4, S5, wA, wB, buf0, buf1);
        step(cc + 5, S5, S6, wB, wA, buf1, buf0);
        step(cc + 6, S6, S7, wA, wB, buf0, buf1);
        step(cc + 7, S7, S0, wB, wA, buf1, buf0);
    }

    // ---- epilogue: logits -> LDS (C/D: col=lane&15 -> expert,
    // row=(lane>>4)*4+reg -> token) ----
    const float bb = b[wid * 16 + (lane & 15)];
#pragma unroll
    for (int mf = 0; mf < 4; ++mf)
#pragma unroll
        for (int r = 0; r < 4; ++r) {
            int t = 16 * mf + (lane >> 4) * 4 + r;
            int e = wid * 16 + (lane & 15);
            lg[t * 132 + e] =
                fmaf(acc2[mf][r], 0.000244140625f, acc1[mf][r]) + bb;
        }
    __syncthreads();

    // ---- partial top-8: 4 threads per token, 32 experts each ----
    if (tid < 256) {
        int tt = tid >> 2, p = tid & 3;
        float vals[8]; int idxs[8];
#pragma unroll
        for (int k = 0; k < 8; ++k) { vals[k] = -FLT_MAX; idxs[k] = 0; }
        const float* row = &lg[tt * 132 + p * 32];
        for (int q = 0; q < 32; ++q)
            insert8(vals, idxs, row[q], p * 32 + q);
#pragma unroll
        for (int k = 0; k < 8; ++k) {
            plv[tid * 9 + k] = vals[k];   // stride 9: conflict-free merge
            pli[tid * 9 + k] = idxs[k];
        }
    }
    __syncthreads();

    // ---- merge + softmax + index output (1 thread per token) ----
    float g[8]; int fidx[8];
    const bool active = (tid < MB);
    if (active) {
        float vals[8]; int idxs[8];
#pragma unroll
        for (int k = 0; k < 8; ++k) { vals[k] = -FLT_MAX; idxs[k] = 0; }
        for (int p = 0; p < 4; ++p) {
#pragma unroll
            for (int k = 0; k < 8; ++k)
                insert8(vals, idxs, plv[(tid * 4 + p) * 9 + k], pli[(tid * 4 + p) * 9 + k]);
        }
        float mx = vals[0];
        float s = 0.0f;
#pragma unroll
        for (int k = 0; k < 8; ++k) { g[k] = __expf(vals[k] - mx); s += g[k]; }
        float inv = 1.0f / s;
#pragma unroll
        for (int k = 0; k < 8; ++k) { g[k] *= inv; fidx[k] = idxs[k]; }
        // indices written as float values (whole out buffer is read back as f32)
#pragma unroll
        for (int k = 0; k < 8; ++k)
            out_idx[(size_t)(tok0 + tid) * KTOP + k] = (float)idxs[k];
    }
    // zero dense gate rows (merge no longer reads lg)
    for (int f = tid; f < MB * 132; f += NTHR) lg[f] = 0.0f;
    __syncthreads();

    if (active) {
#pragma unroll
        for (int k = 0; k < 8; ++k) lg[tid * 132 + fidx[k]] = g[k];
    }
    __syncthreads();

    // ---- coalesced dense copy-out ----
    for (int f = tid; f < MB * (NEXP / 4); f += NTHR) {
        int m = f >> 5, e4 = f & 31;
        float4 v = *(const float4*)&lg[m * 132 + e4 * 4];
        ((float4*)out_gates)[(size_t)(tok0 + m) * (NEXP / 4) + e4] = v;
    }
}

extern "C" void kernel_launch(void* const* d_in, const int* in_sizes, int n_in,
                              void* d_out, int out_size, void* d_ws, size_t ws_size,
                              hipStream_t stream) {
    const float* x = (const float*)d_in[0];   // [B,N,D] f32
    const float* W = (const float*)d_in[1];   // [E,D]   f32
    const float* b = (const float*)d_in[2];   // [E]     f32

    float* out_gates = (float*)d_out;                       // [B,N,E] f32
    float* out_idx   = out_gates + (size_t)TOKENS * NEXP;   // [B,N,K] as f32

    uint4* wf = (uint4*)d_ws;   // 1 MB: W fp16 h/m fragment tables

    wfrag_kernel<<<dim3(WFRAG_N / 256), dim3(256), 0, stream>>>(W, wf);
    router_kernel<<<dim3(TOKENS / MB), dim3(NTHR), 0, stream>>>(x, wf, b, out_gates, out_idx);
}